// Round 15
// baseline (6912.063 us; speedup 1.0000x reference)
//
#include <hip/hip_runtime.h>

#define NB 2048
#define NJ 23
#define NH 512
#define LN_EPS 1e-5f
#define RSQRT2 0.70710678118654752440f

typedef __attribute__((ext_vector_type(4))) float f32x4;
typedef __attribute__((ext_vector_type(8))) short s16x8;
typedef __attribute__((ext_vector_type(4))) short s16x4;

__device__ __forceinline__ float gelu_f(float x){ return 0.5f*x*(1.0f+erff(x*RSQRT2)); }
__device__ __forceinline__ float2 f2(float x, float y){ float2 r; r.x=x; r.y=y; return r; }
__device__ __forceinline__ float2 f2s(float x){ return f2(x,x); }
__device__ __forceinline__ float2 fma2s(float s, float2 b, float2 c){ return f2(fmaf(s,b.x,c.x), fmaf(s,b.y,c.y)); }

__device__ __forceinline__ void fma4(float4& a, float s, const float4& v){
  a.x = fmaf(s, v.x, a.x); a.y = fmaf(s, v.y, a.y);
  a.z = fmaf(s, v.z, a.z); a.w = fmaf(s, v.w, a.w);
}

// round-to-nearest-even float -> bf16
__device__ __forceinline__ short f2bf(float x){
  unsigned u = __float_as_uint(x);
  u = (u + 0x7FFFu + ((u >> 16) & 1u)) >> 16;
  return (short)u;
}

// async global->LDS, 16B per lane; lds base must be wave-uniform (HW adds lane*16)
__device__ __forceinline__ void g2l16(float* lds, const float* g){
  __builtin_amdgcn_global_load_lds(
    (const __attribute__((address_space(1))) void*)g,
    (__attribute__((address_space(3))) void*)lds,
    16, 0, 0);
}

__device__ __forceinline__ unsigned long long shfl_xor_u64(unsigned long long v, int m){
  int lo = __shfl_xor((int)(unsigned)(v & 0xffffffffULL), m);
  int hi = __shfl_xor((int)(unsigned)(v >> 32), m);
  return ((unsigned long long)(unsigned)hi << 32) | (unsigned long long)(unsigned)lo;
}

// ---------- row stats over 23 rows; xc = per-thread column t (512 threads) ----------
__device__ __forceinline__ void row_stats512(const float* xc, float* Lbuf, float* mrs, int t){
  __syncthreads();
  #pragma unroll
  for (int j=0;j<NJ;j++) Lbuf[j*NH + t] = xc[j];
  __syncthreads();
  int wv = t>>6, lane = t&63;
  for (int r = wv; r < NJ; r += 8){
    const float* row = Lbuf + r*NH;
    float4 v0 = *(const float4*)(row + lane*8);
    float4 v1 = *(const float4*)(row + lane*8 + 4);
    float s = v0.x+v0.y+v0.z+v0.w + v1.x+v1.y+v1.z+v1.w;
    #pragma unroll
    for (int o=32;o;o>>=1) s += __shfl_xor(s, o);
    float m = s * (1.0f/512.0f);
    float d, q = 0.f;
    d=v0.x-m; q+=d*d; d=v0.y-m; q+=d*d; d=v0.z-m; q+=d*d; d=v0.w-m; q+=d*d;
    d=v1.x-m; q+=d*d; d=v1.y-m; q+=d*d; d=v1.z-m; q+=d*d; d=v1.w-m; q+=d*d;
    #pragma unroll
    for (int o=32;o;o>>=1) q += __shfl_xor(q, o);
    if (lane==0){
      mrs[r] = m;
      mrs[NJ+r] = 1.0f / sqrtf(q*(1.0f/512.0f) + LN_EPS);
    }
  }
  __syncthreads();
}

// ================= pose -> X  ([47104 x 9] @ [9 x 512]) =================
__global__ __launch_bounds__(512) void k_start(
  const float* __restrict__ pose, const float* __restrict__ start_w,
  const float* __restrict__ start_b, float* __restrict__ X)
{
  __shared__ float psm[NJ*9];
  int t = threadIdx.x, b = blockIdx.x;
  if (t < NJ*9) psm[t] = pose[b*NJ*9 + t];
  __syncthreads();
  float wreg[9];
  #pragma unroll
  for (int c=0;c<9;c++) wreg[c] = start_w[c*NH + t];
  float sb = start_b[t];
  #pragma unroll
  for (int j=0;j<NJ;j++){
    float a = sb;
    #pragma unroll
    for (int c=0;c<9;c++) a = fmaf(psm[j*9+c], wreg[c], a);
    X[(size_t)(b*NJ+j)*NH + t] = a;
  }
}

// ================= token mixer: X += tokenMLP(LN1(X)); Y = LN2(X) =================
// launch_bounds(512,1): lift the 128-VGPR default cap. R14 profile: VGPR=128-pinned +
// WRITE 418MB vs 192MB logical = scratch spill (live set xc+tn+yacc+u/gu ~ 110 regs).
// tn[] hoisted explicitly (loop-invariant across c) — same math order, fewer VALU ops.
__global__ __launch_bounds__(512, 1) void k_tok(
  float* __restrict__ X, float* __restrict__ Y,
  const float* __restrict__ ln1, const float* __restrict__ tw1, const float* __restrict__ tb1,
  const float* __restrict__ tw2, const float* __restrict__ tb2, const float* __restrict__ ln2)
{
  __shared__ float Lbuf[NJ*NH];
  __shared__ float tw1s[NJ*64];     // [j][c]
  __shared__ float tw2sT[NJ*64];    // transposed: [j][c]
  __shared__ float mrs[2*NJ];
  int t = threadIdx.x, b = blockIdx.x;
  for (int i=t; i<NJ*64; i+=512) tw1s[i] = tw1[i];
  for (int i=t; i<NJ*64; i+=512){ int j = i>>6, c = i&63; tw2sT[i] = tw2[c*NJ + j]; }
  float xc[NJ];
  #pragma unroll
  for (int j=0;j<NJ;j++) xc[j] = X[(size_t)(b*NJ+j)*NH + t];
  row_stats512(xc, Lbuf, mrs, t);    // barriers also cover the weight staging
  float g1 = ln1[t], b1 = ln1[NH+t];
  float tn[NJ];
  #pragma unroll
  for (int j=0;j<NJ;j++) tn[j] = fmaf((xc[j]-mrs[j])*mrs[NJ+j], g1, b1);
  float yacc[NJ];
  #pragma unroll
  for (int j=0;j<NJ;j++) yacc[j] = tb2[j];
  for (int c=0;c<64;c+=8){
    float u[8];
    #pragma unroll
    for (int i=0;i<8;i++) u[i] = tb1[c+i];
    #pragma unroll
    for (int j=0;j<NJ;j++){
      float tnj = tn[j];
      float4 w0 = *(const float4*)(tw1s + j*64 + c);
      float4 w1 = *(const float4*)(tw1s + j*64 + c + 4);
      u[0]=fmaf(w0.x,tnj,u[0]); u[1]=fmaf(w0.y,tnj,u[1]); u[2]=fmaf(w0.z,tnj,u[2]); u[3]=fmaf(w0.w,tnj,u[3]);
      u[4]=fmaf(w1.x,tnj,u[4]); u[5]=fmaf(w1.y,tnj,u[5]); u[6]=fmaf(w1.z,tnj,u[6]); u[7]=fmaf(w1.w,tnj,u[7]);
    }
    float gu[8];
    #pragma unroll
    for (int i=0;i<8;i++) gu[i] = gelu_f(u[i]);
    #pragma unroll
    for (int j=0;j<NJ;j++){
      float4 w0 = *(const float4*)(tw2sT + j*64 + c);
      float4 w1 = *(const float4*)(tw2sT + j*64 + c + 4);
      float a = yacc[j];
      a=fmaf(w0.x,gu[0],a); a=fmaf(w0.y,gu[1],a); a=fmaf(w0.z,gu[2],a); a=fmaf(w0.w,gu[3],a);
      a=fmaf(w1.x,gu[4],a); a=fmaf(w1.y,gu[5],a); a=fmaf(w1.z,gu[6],a); a=fmaf(w1.w,gu[7],a);
      yacc[j] = a;
    }
  }
  #pragma unroll
  for (int j=0;j<NJ;j++) xc[j] += yacc[j];
  #pragma unroll
  for (int j=0;j<NJ;j++) X[(size_t)(b*NJ+j)*NH + t] = xc[j];   // resid in place
  row_stats512(xc, Lbuf, mrs, t);
  float g2 = ln2[t], b2 = ln2[NH+t];
  #pragma unroll
  for (int j=0;j<NJ;j++)
    Y[(size_t)(b*NJ+j)*NH + t] = fmaf((xc[j]-mrs[j])*mrs[NJ+j], g2, b2);
}

// ================= enc final: Y = tokproj(LNf(X)) =================
__global__ __launch_bounds__(512) void k_tokf(
  const float* __restrict__ X, float* __restrict__ Y,
  const float* __restrict__ lnf, const float* __restrict__ tokw, const float* __restrict__ tokb)
{
  __shared__ float Lbuf[NJ*NH];
  __shared__ float mrs[2*NJ];
  __shared__ float tokws[NJ*NJ];
  __shared__ float tokbs[NJ];
  int t = threadIdx.x, b = blockIdx.x;
  for (int i=t; i<NJ*NJ; i+=512) tokws[i] = tokw[i];   // 529 entries: strided loop
  if (t<NJ) tokbs[t] = tokb[t];
  float xc[NJ];
  #pragma unroll
  for (int j=0;j<NJ;j++) xc[j] = X[(size_t)(b*NJ+j)*NH + t];
  row_stats512(xc, Lbuf, mrs, t);
  float gF = lnf[t], bF = lnf[NH+t];
  float xt[NJ];
  #pragma unroll
  for (int j=0;j<NJ;j++) xt[j] = tokbs[j];
  #pragma unroll
  for (int jp=0;jp<NJ;jp++){
    float v = fmaf((xc[jp]-mrs[jp])*mrs[NJ+jp], gF, bF);
    #pragma unroll
    for (int j=0;j<NJ;j++) xt[j] = fmaf(tokws[jp*NJ+j], v, xt[j]);
  }
  #pragma unroll
  for (int j=0;j<NJ;j++) Y[(size_t)(b*NJ+j)*NH + t] = xt[j];
}

// ================= dec start: Y = tokproj(gather(codebook, idx)) =================
__global__ __launch_bounds__(512) void k_dtok(
  const unsigned long long* __restrict__ packed, const float* __restrict__ cb,
  float* __restrict__ Y, const float* __restrict__ tokw, const float* __restrict__ tokb)
{
  __shared__ float tokws[NJ*NJ];
  __shared__ float tokbs[NJ];
  __shared__ int idxs[NJ];
  int t = threadIdx.x, b = blockIdx.x;
  for (int i=t; i<NJ*NJ; i+=512) tokws[i] = tokw[i];   // 529 entries: strided loop
  if (t<NJ){
    tokbs[t] = tokb[t];
    idxs[t]  = (int)(unsigned)(packed[b*NJ + t] & 0xffffffffULL);
  }
  __syncthreads();
  float xt[NJ];
  #pragma unroll
  for (int j=0;j<NJ;j++) xt[j] = tokbs[j];
  #pragma unroll
  for (int jp=0;jp<NJ;jp++){
    float qv = cb[(size_t)idxs[jp]*NH + t];
    #pragma unroll
    for (int j=0;j<NJ;j++) xt[j] = fmaf(tokws[jp*NJ+j], qv, xt[j]);
  }
  #pragma unroll
  for (int j=0;j<NJ;j++) Y[(size_t)(b*NJ+j)*NH + t] = xt[j];
}

// ================= fp32 channel GEMM (ENCODER only; R11-best config) =================
#define BK 8
#define ATS 68
template<int OP>
__global__ __launch_bounds__(512) void k_gemm(
  const float* __restrict__ A, const float* __restrict__ W, const float* __restrict__ bias,
  const float* __restrict__ R, float* __restrict__ OUT)
{
  __shared__ float asT[2][BK][ATS];
  __shared__ float wt[2][BK][512];
  int t = threadIdx.x;
  int m0 = blockIdx.x * 64;
  int ct = t & 63;
  int rg = t >> 6;
  int r0 = rg * 8;
  int cLo = ct*4, cHi = 256 + ct*4;
  int lane = t & 63, wv = t >> 6;
  int sar = t >> 3, sak = t & 7;
  const float* Aptr = A + (size_t)(m0+sar)*NH + sak;

  float4 accLo[8], accHi[8];
  #pragma unroll
  for (int i=0;i<8;i++){ accLo[i]=make_float4(0,0,0,0); accHi[i]=make_float4(0,0,0,0); }

  {
    g2l16(&wt[0][wv][0],   W + (size_t)wv*NH + lane*4);
    g2l16(&wt[0][wv][256], W + (size_t)wv*NH + 256 + lane*4);
    asT[0][sak][sar] = *Aptr;
  }
  __syncthreads();

  for (int kt=0; kt<64; ++kt){
    int cur = kt&1, nxt = cur^1;
    float av = 0.f;
    if (kt+1 < 64){
      int kc = (kt+1)*BK;
      av = Aptr[kc];
      g2l16(&wt[nxt][wv][0],   W + (size_t)(kc+wv)*NH + lane*4);
      g2l16(&wt[nxt][wv][256], W + (size_t)(kc+wv)*NH + 256 + lane*4);
    }
    #pragma unroll 2
    for (int k=0;k<BK;k++){
      float4 a0 = *(const float4*)&asT[cur][k][r0];
      float4 a1 = *(const float4*)&asT[cur][k][r0+4];
      float4 w0 = *(const float4*)&wt[cur][k][cLo];
      float4 w1 = *(const float4*)&wt[cur][k][cHi];
      fma4(accLo[0], a0.x, w0); fma4(accHi[0], a0.x, w1);
      fma4(accLo[1], a0.y, w0); fma4(accHi[1], a0.y, w1);
      fma4(accLo[2], a0.z, w0); fma4(accHi[2], a0.z, w1);
      fma4(accLo[3], a0.w, w0); fma4(accHi[3], a0.w, w1);
      fma4(accLo[4], a1.x, w0); fma4(accHi[4], a1.x, w1);
      fma4(accLo[5], a1.y, w0); fma4(accHi[5], a1.y, w1);
      fma4(accLo[6], a1.z, w0); fma4(accHi[6], a1.z, w1);
      fma4(accLo[7], a1.w, w0); fma4(accHi[7], a1.w, w1);
    }
    if (kt+1 < 64) asT[nxt][sak][sar] = av;
    __syncthreads();
  }
  float4 bsLo = *(const float4*)(bias + cLo);
  float4 bsHi = *(const float4*)(bias + cHi);
  #pragma unroll
  for (int i=0;i<8;i++){
    size_t row = (size_t)(m0 + r0 + i);
    float4 v0 = accLo[i], v1 = accHi[i];
    v0.x+=bsLo.x; v0.y+=bsLo.y; v0.z+=bsLo.z; v0.w+=bsLo.w;
    v1.x+=bsHi.x; v1.y+=bsHi.y; v1.z+=bsHi.z; v1.w+=bsHi.w;
    if (OP==0){
      v0.x=gelu_f(v0.x); v0.y=gelu_f(v0.y); v0.z=gelu_f(v0.z); v0.w=gelu_f(v0.w);
      v1.x=gelu_f(v1.x); v1.y=gelu_f(v1.y); v1.z=gelu_f(v1.z); v1.w=gelu_f(v1.w);
    } else if (OP==1){
      float4 r0v = *(const float4*)(R + row*NH + cLo);
      float4 r1v = *(const float4*)(R + row*NH + cHi);
      v0.x+=r0v.x; v0.y+=r0v.y; v0.z+=r0v.z; v0.w+=r0v.w;
      v1.x+=r1v.x; v1.y+=r1v.y; v1.z+=r1v.z; v1.w+=r1v.w;
    }
    *(float4*)(OUT + row*NH + cLo) = v0;
    *(float4*)(OUT + row*NH + cHi) = v1;
  }
}

// ================= W pre-split: fp32 [512x512] -> bf16 K-tiled [kt][col][32] =================
__global__ __launch_bounds__(512) void k_wsplit(const float* __restrict__ W, short* __restrict__ out){
  int kt = blockIdx.x, t = threadIdx.x;
  int kb = kt*32;
  short* dst = out + (size_t)kt*16384 + (size_t)t*32;
  #pragma unroll 8
  for (int kk=0; kk<32; ++kk)
    dst[kk] = f2bf(W[(size_t)(kb+kk)*NH + t]);
}

// ================= bf16 MFMA channel GEMM, preconverted W (DECODER) =================
#define WPCH 40
template<int OP>
__global__ __launch_bounds__(512) void k_gemm_bfp(
  const float* __restrict__ A, const short* __restrict__ Wpk, const float* __restrict__ bias,
  const float* __restrict__ R, float* __restrict__ OUT)
{
  __shared__ short Wl[512*WPCH];   // 40 KB
  __shared__ short Al[64*WPCH];    // 5 KB
  int t = threadIdx.x;
  int m0 = blockIdx.x * 64;
  int l = t & 63, w = t >> 6;
  int g = l >> 4, lm = l & 15;
  int ar = t >> 3, ak0 = (t & 7) * 4;  // A stage: row, k-base

  f32x4 acc[4][4];
  #pragma unroll
  for (int m=0;m<4;m++)
    #pragma unroll
    for (int n=0;n<4;n++){ acc[m][n][0]=0.f; acc[m][n][1]=0.f; acc[m][n][2]=0.f; acc[m][n][3]=0.f; }

  for (int kt=0; kt<16; ++kt){
    __syncthreads();               // prior frag reads done before overwrite
    // stage W tile (32KB contiguous) -> Wl[col][k] pitch 40
    const short* src = Wpk + (size_t)kt*16384;
    #pragma unroll
    for (int i=0;i<4;i++){
      int piece = t + i*512;
      s16x8 v = *(const s16x8*)(src + (size_t)piece*8);
      int col = piece >> 2, pc = piece & 3;
      *(s16x8*)&Wl[col*WPCH + pc*8] = v;
    }
    // stage A[64x32] -> Al[row][k]
    {
      float4 a4 = *(const float4*)(A + (size_t)(m0+ar)*NH + kt*32 + ak0);
      s16x4 v; v[0]=f2bf(a4.x); v[1]=f2bf(a4.y); v[2]=f2bf(a4.z); v[3]=f2bf(a4.w);
      *(s16x4*)&Al[ar*WPCH + ak0] = v;
    }
    __syncthreads();
    // fragments + MFMA
    s16x8 af0 = *(const s16x8*)&Al[(lm +  0)*WPCH + g*8];
    s16x8 af1 = *(const s16x8*)&Al[(lm + 16)*WPCH + g*8];
    s16x8 af2 = *(const s16x8*)&Al[(lm + 32)*WPCH + g*8];
    s16x8 af3 = *(const s16x8*)&Al[(lm + 48)*WPCH + g*8];
    #pragma unroll
    for (int n=0;n<4;n++){
      int col = w*64 + n*16 + lm;
      s16x8 bfr = *(const s16x8*)&Wl[col*WPCH + g*8];
      acc[0][n] = __builtin_amdgcn_mfma_f32_16x16x32_bf16(af0, bfr, acc[0][n], 0,0,0);
      acc[1][n] = __builtin_amdgcn_mfma_f32_16x16x32_bf16(af1, bfr, acc[1][n], 0,0,0);
      acc[2][n] = __builtin_amdgcn_mfma_f32_16x16x32_bf16(af2, bfr, acc[2][n], 0,0,0);
      acc[3][n] = __builtin_amdgcn_mfma_f32_16x16x32_bf16(af3, bfr, acc[3][n], 0,0,0);
    }
  }
  // epilogue (C/D: col=lane&15, row=(lane>>4)*4+reg — HW-verified)
  #pragma unroll
  for (int n=0;n<4;n++){
    int col = w*64 + n*16 + lm;
    float bs = bias[col];
    #pragma unroll
    for (int m=0;m<4;m++){
      #pragma unroll
      for (int r=0;r<4;r++){
        int row = m0 + m*16 + g*4 + r;
        float v = acc[m][n][r] + bs;
        if (OP==0) v = gelu_f(v);
        else if (OP==1) v += R[(size_t)row*NH + col];
        OUT[(size_t)row*NH + col] = v;
      }
    }
  }
}

// ================= norms =================
__global__ void pct_norm_kernel(const float* __restrict__ e, const float* __restrict__ cb,
                                float* __restrict__ enorm, float* __restrict__ cnorm){
  int gw = (blockIdx.x*256 + threadIdx.x)>>6;
  int lane = threadIdx.x & 63;
  int nw = gridDim.x*4;
  for (int r = gw; r < 2048 + 47104; r += nw){
    const float* src = (r < 2048) ? (cb + (size_t)r*512) : (e + (size_t)(r-2048)*512);
    float4 v0 = *(const float4*)(src + lane*8);
    float4 v1 = *(const float4*)(src + lane*8 + 4);
    float q = v0.x*v0.x+v0.y*v0.y+v0.z*v0.z+v0.w*v0.w
            + v1.x*v1.x+v1.y*v1.y+v1.z*v1.z+v1.w*v1.w;
    #pragma unroll
    for (int o=32;o;o>>=1) q += __shfl_xor(q, o);
    if (lane==0){ if (r<2048) cnorm[r]=q; else enorm[r-2048]=q; }
  }
}

// ================= VQ distance GEMM + fused argmin =================
#define VBM 64
#define VBN 128
#define VBK 32
#define ETS 68
#define CTS 132
__global__ __launch_bounds__(256, 4) void pct_vq_kernel(
  const float* __restrict__ e, const float* __restrict__ cb,
  const float* __restrict__ enorm, const float* __restrict__ cnorm,
  unsigned long long* __restrict__ packed)
{
  __shared__ float Et[VBK*ETS];
  __shared__ float Ct[VBK*CTS];
  int t = threadIdx.x;
  int row0 = blockIdx.x * VBM;
  int n00  = blockIdx.y * VBN;
  int m0 = (t>>4)<<2;
  int g  = t&15;
  int nA = g*4, nB = 64 + g*4;
  float2 acc[2][8];
  #pragma unroll
  for (int p=0;p<2;p++)
    #pragma unroll
    for (int j=0;j<8;j++) acc[p][j] = f2s(0.f);
  int er = t>>2, eq = t&3;
  int cn = t>>1, ch = t&1;
  for (int kc=0; kc<512; kc+=VBK){
    __syncthreads();
    {
      const float4* src = (const float4*)(e + (size_t)(row0+er)*512 + kc + eq*8);
      float4 a = src[0], bv = src[1];
      float* d0 = Et + (eq*8)*ETS + er;
      d0[0*ETS]=a.x;  d0[1*ETS]=a.y;  d0[2*ETS]=a.z;  d0[3*ETS]=a.w;
      d0[4*ETS]=bv.x; d0[5*ETS]=bv.y; d0[6*ETS]=bv.z; d0[7*ETS]=bv.w;
    }
    {
      const float4* src = (const float4*)(cb + (size_t)(n00+cn)*512 + kc + ch*16);
      float4 a=src[0], b2=src[1], c2=src[2], d2=src[3];
      float* d0 = Ct + (ch*16)*CTS + cn;
      d0[0*CTS]=a.x;   d0[1*CTS]=a.y;   d0[2*CTS]=a.z;   d0[3*CTS]=a.w;
      d0[4*CTS]=b2.x;  d0[5*CTS]=b2.y;  d0[6*CTS]=b2.z;  d0[7*CTS]=b2.w;
      d0[8*CTS]=c2.x;  d0[9*CTS]=c2.y;  d0[10*CTS]=c2.z; d0[11*CTS]=c2.w;
      d0[12*CTS]=d2.x; d0[13*CTS]=d2.y; d0[14*CTS]=d2.z; d0[15*CTS]=d2.w;
    }
    __syncthreads();
    #pragma unroll 8
    for (int k=0;k<VBK;k++){
      float4 av = *(const float4*)(Et + k*ETS + m0);
      float4 b0 = *(const float4*)(Ct + k*CTS + nA);
      float4 b1 = *(const float4*)(Ct + k*CTS + nB);
      float2 a01 = f2(av.x, av.y), a23 = f2(av.z, av.w);
      float bs[8] = {b0.x,b0.y,b0.z,b0.w,b1.x,b1.y,b1.z,b1.w};
      #pragma unroll
      for (int j=0;j<8;j++){
        acc[0][j] = fma2s(bs[j], a01, acc[0][j]);
        acc[1][j] = fma2s(bs[j], a23, acc[1][j]);
      }
    }
  }
  unsigned long long key[4];
  #pragma unroll
  for (int i=0;i<4;i++){
    float en = enorm[row0 + m0 + i];
    unsigned long long kk = ~0ULL;
    #pragma unroll
    for (int j=0;j<8;j++){
      float2 av = acc[i>>1][j];
      float dot = (i&1) ? av.y : av.x;
      int code = n00 + ((j<4) ? (nA + j) : (nB + j - 4));
      float dd = (en + cnorm[code]) - 2.0f*dot;
      unsigned long long kv = ((unsigned long long)__float_as_uint(dd)<<32) | (unsigned long long)(unsigned)code;
      kk = kv < kk ? kv : kk;
    }
    key[i] = kk;
  }
  #pragma unroll
  for (int o=1;o<16;o<<=1){
    #pragma unroll
    for (int i=0;i<4;i++){
      unsigned long long other = shfl_xor_u64(key[i], o);
      key[i] = other < key[i] ? other : key[i];
    }
  }
  if ((t&15)==0){
    #pragma unroll
    for (int i=0;i<4;i++) atomicMin(packed + row0 + m0 + i, key[i]);
  }
}

// ================= idx output + latent loss =================
__global__ void pct_loss_idx_kernel(const float* __restrict__ e, const float* __restrict__ cb,
                                    const unsigned long long* __restrict__ packed,
                                    float* __restrict__ idx_out, float* __restrict__ partials){
  int t = threadIdx.x, lane = t&63;
  int gw = (blockIdx.x*256 + t)>>6;
  int nw = gridDim.x*4;
  float part = 0.f;
  for (int r=gw; r<47104; r+=nw){
    unsigned long long pk = packed[r];
    int idx = (int)(unsigned)(pk & 0xffffffffULL);
    if (lane==0) idx_out[r] = (float)idx;
    const float4* ep = (const float4*)(e + (size_t)r*512);
    const float4* cp = (const float4*)(cb + (size_t)idx*512);
    #pragma unroll
    for (int i=0;i<2;i++){
      float4 ev = ep[lane*2+i], cv = cp[lane*2+i];
      float dx=cv.x-ev.x, dy=cv.y-ev.y, dz=cv.z-ev.z, dw=cv.w-ev.w;
      part += dx*dx+dy*dy+dz*dz+dw*dw;
    }
  }
  #pragma unroll
  for (int o=32;o;o>>=1) part += __shfl_xor(part, o);
  __shared__ float wsum[4];
  if (lane==0) wsum[t>>6] = part;
  __syncthreads();
  if (t==0) partials[blockIdx.x] = wsum[0]+wsum[1]+wsum[2]+wsum[3];
}

__global__ void pct_loss_final_kernel(const float* __restrict__ partials, float* __restrict__ loss){
  float s=0.f;
  for (int i=threadIdx.x; i<256; i+=64) s += partials[i];
  #pragma unroll
  for (int o=32;o;o>>=1) s += __shfl_xor(s, o);
  if (threadIdx.x==0) *loss = s * (1.0f/(47104.0f*512.0f));
}

// ================= dec final: rec = LNf(X) @ rec_w + rec_b =================
__global__ __launch_bounds__(512) void k_decfinal(
  const float* __restrict__ X, const float* __restrict__ lnfd,
  const float* __restrict__ rec_w, const float* __restrict__ rec_b,
  float* __restrict__ rec_out)
{
  __shared__ float Lbuf[NJ*NH];          // for row_stats
  __shared__ float Ln[NJ*516];           // padded normalized rows
  __shared__ float rws[NH*9];
  __shared__ float mrs[2*NJ];
  int t = threadIdx.x, b = blockIdx.x;
  for (int i=t;i<NH*9;i+=512) rws[i] = rec_w[i];
  float xc[NJ];
  #pragma unroll
  for (int j=0;j<NJ;j++) xc[j] = X[(size_t)(b*NJ+j)*NH + t];
  row_stats512(xc, Lbuf, mrs, t);
  float gF = lnfd[t], bF = lnfd[NH+t];
  #pragma unroll
  for (int j=0;j<NJ;j++)
    Ln[j*516 + t] = fmaf((xc[j]-mrs[j])*mrs[NJ+j], gF, bF);
  __syncthreads();
  if (t < NJ*9){
    int j = t/9, c = t - j*9;
    float a = rec_b[c];
    const float* row = Ln + j*516;
    for (int h=0;h<NH;h++) a = fmaf(row[h], rws[h*9+c], a);
    rec_out[(size_t)(b*NJ+j)*9 + c] = a;
  }
}

// ================= launch =================
extern "C" void kernel_launch(void* const* d_in, const int* in_sizes, int n_in,
                              void* d_out, int out_size, void* d_ws, size_t ws_size,
                              hipStream_t stream) {
  (void)in_sizes; (void)n_in; (void)out_size; (void)ws_size;
  const float* pose        = (const float*)d_in[0];
  const float* start_w     = (const float*)d_in[1];
  const float* start_b     = (const float*)d_in[2];
  const float* enc_ln1     = (const float*)d_in[3];
  const float* enc_tw1     = (const float*)d_in[4];
  const float* enc_tb1     = (const float*)d_in[5];
  const float* enc_tw2     = (const float*)d_in[6];
  const float* enc_tb2     = (const float*)d_in[7];
  const float* enc_ln2     = (const float*)d_in[8];
  const float* enc_cw1     = (const float*)d_in[9];
  const float* enc_cb1     = (const float*)d_in[10];
  const float* enc_cw2     = (const float*)d_in[11];
  const float* enc_cb2     = (const float*)d_in[12];
  const float* enc_lnf     = (const float*)d_in[13];
  const float* tok_w       = (const float*)d_in[14];
  const float* tok_b       = (const float*)d_in[15];
  const float* feat_w      = (const float*)d_in[16];
  const float* feat_b      = (const float*)d_in[17];
  const float* codebook    = (const float*)d_in[18];
  const float* dec_tok_w   = (const float*)d_in[19];
  const float* dec_tok_b   = (const float*)d_in[20];
  const float* dec_start_w = (const float*)d_in[21];
  const float* dec_start_b = (const float*)d_in[22];
  const float* dec_ln1     = (const float*)d_in[23];
  const float* dec_tw1     = (const float*)d_in[24];
  const float* dec_tb1     = (const float*)d_in[25];
  const float* dec_tw2     = (const float*)d_in[26];
  const float* dec_tb2     = (const float*)d_in[27];
  const float* dec_ln2     = (const float*)d_in[28];
  const float* dec_cw1     = (const float*)d_in[29];
  const float* dec_cb1     = (const float*)d_in[30];
  const float* dec_cw2     = (const float*)d_in[31];
  const float* dec_cb2     = (const float*)d_in[32];
  const float* dec_lnf     = (const float*)d_in[33];
  const float* rec_w       = (const float*)d_in[34];
  const float* rec_b       = (const float*)d_in[35];

  const size_t ACT = (size_t)47104*512;     // floats per activation buffer
  float* X = (float*)d_ws;
  float* Y = X + ACT;
  unsigned long long* packed = (unsigned long long*)(Y + ACT);
  float* cnorm  = (float*)((char*)packed + (size_t)47104*8);
  float* enormp = cnorm + 2048;
  float* partials = enormp + 47104;
  short* decWpk  = (short*)(partials + 256);   // 9 x 262144 shorts = 4.7 MB

  float* rec_out  = (float*)d_out;
  float* idx_out  = rec_out + 423936;
  float* loss_out = idx_out + 47104;

  (void)hipMemsetAsync(packed, 0xFF, (size_t)47104*8, stream);

  // pre-split decoder weights to bf16 K-tiled layout (order: start, (cw1,cw2)x4)
  const size_t WSZ = (size_t)512*512;   // shorts per weight
  k_wsplit<<<16, 512, 0, stream>>>(dec_start_w, decWpk);
  for (int l=0;l<4;l++){
    k_wsplit<<<16, 512, 0, stream>>>(dec_cw1 + l*(NH*NH), decWpk + (1 + 2*l)*WSZ);
    k_wsplit<<<16, 512, 0, stream>>>(dec_cw2 + l*(NH*NH), decWpk + (2 + 2*l)*WSZ);
  }

  k_start<<<NB, 512, 0, stream>>>(pose, start_w, start_b, X);

  const int GG = 736;   // 47104 / 64
  for (int l=0;l<4;l++){
    k_tok<<<NB, 512, 0, stream>>>(X, Y,
      enc_ln1 + l*1024, enc_tw1 + l*(NJ*64), enc_tb1 + l*64,
      enc_tw2 + l*(64*NJ), enc_tb2 + l*NJ, enc_ln2 + l*1024);
    k_gemm<0><<<GG, 512, 0, stream>>>(Y, enc_cw1 + l*(NH*NH), enc_cb1 + l*NH, nullptr, Y);
    k_gemm<1><<<GG, 512, 0, stream>>>(Y, enc_cw2 + l*(NH*NH), enc_cb2 + l*NH, X, X);
  }
  k_tokf<<<NB, 512, 0, stream>>>(X, Y, enc_lnf, tok_w, tok_b);
  k_gemm<2><<<GG, 512, 0, stream>>>(Y, feat_w, feat_b, nullptr, X);   // X = e

  pct_norm_kernel<<<192, 256, 0, stream>>>(X, codebook, enormp, cnorm);
  pct_vq_kernel<<<dim3(736,16), 256, 0, stream>>>(X, codebook, enormp, cnorm, packed);
  pct_loss_idx_kernel<<<256, 256, 0, stream>>>(X, codebook, packed, idx_out, partials);
  pct_loss_final_kernel<<<1, 64, 0, stream>>>(partials, loss_out);

  k_dtok<<<NB, 512, 0, stream>>>(packed, codebook, Y, dec_tok_w, dec_tok_b);
  k_gemm_bfp<2><<<GG, 512, 0, stream>>>(Y, decWpk, dec_start_b, nullptr, X);

  for (int l=0;l<4;l++){
    k_tok<<<NB, 512, 0, stream>>>(X, Y,
      dec_ln1 + l*1024, dec_tw1 + l*(NJ*64), dec_tb1 + l*64,
      dec_tw2 + l*(64*NJ), dec_tb2 + l*NJ, dec_ln2 + l*1024);
    k_gemm_bfp<0><<<GG, 512, 0, stream>>>(Y, decWpk + (1 + 2*l)*WSZ, dec_cb1 + l*NH, nullptr, Y);
    k_gemm_bfp<1><<<GG, 512, 0, stream>>>(Y, decWpk + (2 + 2*l)*WSZ, dec_cb2 + l*NH, X, X);
  }
  k_decfinal<<<NB, 512, 0, stream>>>(X, dec_lnf, rec_w, rec_b, rec_out);
}

// Round 16
// 6858.866 us; speedup vs baseline: 1.0078x; 1.0078x over previous
//
#include <hip/hip_runtime.h>

#define NB 2048
#define NJ 23
#define NH 512
#define LN_EPS 1e-5f
#define RSQRT2 0.70710678118654752440f

typedef __attribute__((ext_vector_type(4))) float f32x4;
typedef __attribute__((ext_vector_type(8))) short s16x8;
typedef __attribute__((ext_vector_type(4))) short s16x4;

__device__ __forceinline__ float gelu_f(float x){ return 0.5f*x*(1.0f+erff(x*RSQRT2)); }
__device__ __forceinline__ float2 f2(float x, float y){ float2 r; r.x=x; r.y=y; return r; }
__device__ __forceinline__ float2 f2s(float x){ return f2(x,x); }
__device__ __forceinline__ float2 fma2s(float s, float2 b, float2 c){ return f2(fmaf(s,b.x,c.x), fmaf(s,b.y,c.y)); }

__device__ __forceinline__ void fma4(float4& a, float s, const float4& v){
  a.x = fmaf(s, v.x, a.x); a.y = fmaf(s, v.y, a.y);
  a.z = fmaf(s, v.z, a.z); a.w = fmaf(s, v.w, a.w);
}

// round-to-nearest-even float -> bf16
__device__ __forceinline__ short f2bf(float x){
  unsigned u = __float_as_uint(x);
  u = (u + 0x7FFFu + ((u >> 16) & 1u)) >> 16;
  return (short)u;
}

// async global->LDS, 16B per lane; lds base must be wave-uniform (HW adds lane*16)
__device__ __forceinline__ void g2l16(float* lds, const float* g){
  __builtin_amdgcn_global_load_lds(
    (const __attribute__((address_space(1))) void*)g,
    (__attribute__((address_space(3))) void*)lds,
    16, 0, 0);
}

__device__ __forceinline__ unsigned long long shfl_xor_u64(unsigned long long v, int m){
  int lo = __shfl_xor((int)(unsigned)(v & 0xffffffffULL), m);
  int hi = __shfl_xor((int)(unsigned)(v >> 32), m);
  return ((unsigned long long)(unsigned)hi << 32) | (unsigned long long)(unsigned)lo;
}

// ---------- row stats over 23 rows; xc = per-thread column t (512 threads) ----------
__device__ __forceinline__ void row_stats512(const float* xc, float* Lbuf, float* mrs, int t){
  __syncthreads();
  #pragma unroll
  for (int j=0;j<NJ;j++) Lbuf[j*NH + t] = xc[j];
  __syncthreads();
  int wv = t>>6, lane = t&63;
  for (int r = wv; r < NJ; r += 8){
    const float* row = Lbuf + r*NH;
    float4 v0 = *(const float4*)(row + lane*8);
    float4 v1 = *(const float4*)(row + lane*8 + 4);
    float s = v0.x+v0.y+v0.z+v0.w + v1.x+v1.y+v1.z+v1.w;
    #pragma unroll
    for (int o=32;o;o>>=1) s += __shfl_xor(s, o);
    float m = s * (1.0f/512.0f);
    float d, q = 0.f;
    d=v0.x-m; q+=d*d; d=v0.y-m; q+=d*d; d=v0.z-m; q+=d*d; d=v0.w-m; q+=d*d;
    d=v1.x-m; q+=d*d; d=v1.y-m; q+=d*d; d=v1.z-m; q+=d*d; d=v1.w-m; q+=d*d;
    #pragma unroll
    for (int o=32;o;o>>=1) q += __shfl_xor(q, o);
    if (lane==0){
      mrs[r] = m;
      mrs[NJ+r] = 1.0f / sqrtf(q*(1.0f/512.0f) + LN_EPS);
    }
  }
  __syncthreads();
}

// ================= pose -> X  ([47104 x 9] @ [9 x 512]) =================
__global__ __launch_bounds__(512) void k_start(
  const float* __restrict__ pose, const float* __restrict__ start_w,
  const float* __restrict__ start_b, float* __restrict__ X)
{
  __shared__ float psm[NJ*9];
  int t = threadIdx.x, b = blockIdx.x;
  if (t < NJ*9) psm[t] = pose[b*NJ*9 + t];
  __syncthreads();
  float wreg[9];
  #pragma unroll
  for (int c=0;c<9;c++) wreg[c] = start_w[c*NH + t];
  float sb = start_b[t];
  #pragma unroll
  for (int j=0;j<NJ;j++){
    float a = sb;
    #pragma unroll
    for (int c=0;c<9;c++) a = fmaf(psm[j*9+c], wreg[c], a);
    X[(size_t)(b*NJ+j)*NH + t] = a;
  }
}

// ================= token mixer: X += tokenMLP(LN1(X)); Y = LN2(X) =================
__global__ __launch_bounds__(512, 1) void k_tok(
  float* __restrict__ X, float* __restrict__ Y,
  const float* __restrict__ ln1, const float* __restrict__ tw1, const float* __restrict__ tb1,
  const float* __restrict__ tw2, const float* __restrict__ tb2, const float* __restrict__ ln2)
{
  __shared__ float Lbuf[NJ*NH];
  __shared__ float tw1s[NJ*64];     // [j][c]
  __shared__ float tw2sT[NJ*64];    // transposed: [j][c]
  __shared__ float mrs[2*NJ];
  int t = threadIdx.x, b = blockIdx.x;
  for (int i=t; i<NJ*64; i+=512) tw1s[i] = tw1[i];
  for (int i=t; i<NJ*64; i+=512){ int j = i>>6, c = i&63; tw2sT[i] = tw2[c*NJ + j]; }
  float xc[NJ];
  #pragma unroll
  for (int j=0;j<NJ;j++) xc[j] = X[(size_t)(b*NJ+j)*NH + t];
  row_stats512(xc, Lbuf, mrs, t);    // barriers also cover the weight staging
  float g1 = ln1[t], b1 = ln1[NH+t];
  float tn[NJ];
  #pragma unroll
  for (int j=0;j<NJ;j++) tn[j] = fmaf((xc[j]-mrs[j])*mrs[NJ+j], g1, b1);
  float yacc[NJ];
  #pragma unroll
  for (int j=0;j<NJ;j++) yacc[j] = tb2[j];
  for (int c=0;c<64;c+=8){
    float u[8];
    #pragma unroll
    for (int i=0;i<8;i++) u[i] = tb1[c+i];
    #pragma unroll
    for (int j=0;j<NJ;j++){
      float tnj = tn[j];
      float4 w0 = *(const float4*)(tw1s + j*64 + c);
      float4 w1 = *(const float4*)(tw1s + j*64 + c + 4);
      u[0]=fmaf(w0.x,tnj,u[0]); u[1]=fmaf(w0.y,tnj,u[1]); u[2]=fmaf(w0.z,tnj,u[2]); u[3]=fmaf(w0.w,tnj,u[3]);
      u[4]=fmaf(w1.x,tnj,u[4]); u[5]=fmaf(w1.y,tnj,u[5]); u[6]=fmaf(w1.z,tnj,u[6]); u[7]=fmaf(w1.w,tnj,u[7]);
    }
    float gu[8];
    #pragma unroll
    for (int i=0;i<8;i++) gu[i] = gelu_f(u[i]);
    #pragma unroll
    for (int j=0;j<NJ;j++){
      float4 w0 = *(const float4*)(tw2sT + j*64 + c);
      float4 w1 = *(const float4*)(tw2sT + j*64 + c + 4);
      float a = yacc[j];
      a=fmaf(w0.x,gu[0],a); a=fmaf(w0.y,gu[1],a); a=fmaf(w0.z,gu[2],a); a=fmaf(w0.w,gu[3],a);
      a=fmaf(w1.x,gu[4],a); a=fmaf(w1.y,gu[5],a); a=fmaf(w1.z,gu[6],a); a=fmaf(w1.w,gu[7],a);
      yacc[j] = a;
    }
  }
  #pragma unroll
  for (int j=0;j<NJ;j++) xc[j] += yacc[j];
  #pragma unroll
  for (int j=0;j<NJ;j++) X[(size_t)(b*NJ+j)*NH + t] = xc[j];   // resid in place
  row_stats512(xc, Lbuf, mrs, t);
  float g2 = ln2[t], b2 = ln2[NH+t];
  #pragma unroll
  for (int j=0;j<NJ;j++)
    Y[(size_t)(b*NJ+j)*NH + t] = fmaf((xc[j]-mrs[j])*mrs[NJ+j], g2, b2);
}

// ================= enc final: Y = tokproj(LNf(X)) =================
__global__ __launch_bounds__(512) void k_tokf(
  const float* __restrict__ X, float* __restrict__ Y,
  const float* __restrict__ lnf, const float* __restrict__ tokw, const float* __restrict__ tokb)
{
  __shared__ float Lbuf[NJ*NH];
  __shared__ float mrs[2*NJ];
  __shared__ float tokws[NJ*NJ];
  __shared__ float tokbs[NJ];
  int t = threadIdx.x, b = blockIdx.x;
  for (int i=t; i<NJ*NJ; i+=512) tokws[i] = tokw[i];   // 529 entries: strided loop
  if (t<NJ) tokbs[t] = tokb[t];
  float xc[NJ];
  #pragma unroll
  for (int j=0;j<NJ;j++) xc[j] = X[(size_t)(b*NJ+j)*NH + t];
  row_stats512(xc, Lbuf, mrs, t);
  float gF = lnf[t], bF = lnf[NH+t];
  float xt[NJ];
  #pragma unroll
  for (int j=0;j<NJ;j++) xt[j] = tokbs[j];
  #pragma unroll
  for (int jp=0;jp<NJ;jp++){
    float v = fmaf((xc[jp]-mrs[jp])*mrs[NJ+jp], gF, bF);
    #pragma unroll
    for (int j=0;j<NJ;j++) xt[j] = fmaf(tokws[jp*NJ+j], v, xt[j]);
  }
  #pragma unroll
  for (int j=0;j<NJ;j++) Y[(size_t)(b*NJ+j)*NH + t] = xt[j];
}

// ================= dec start: Y = tokproj(gather(codebook, idx)) =================
__global__ __launch_bounds__(512) void k_dtok(
  const unsigned long long* __restrict__ packed, const float* __restrict__ cb,
  float* __restrict__ Y, const float* __restrict__ tokw, const float* __restrict__ tokb)
{
  __shared__ float tokws[NJ*NJ];
  __shared__ float tokbs[NJ];
  __shared__ int idxs[NJ];
  int t = threadIdx.x, b = blockIdx.x;
  for (int i=t; i<NJ*NJ; i+=512) tokws[i] = tokw[i];   // 529 entries: strided loop
  if (t<NJ){
    tokbs[t] = tokb[t];
    idxs[t]  = (int)(unsigned)(packed[b*NJ + t] & 0xffffffffULL);
  }
  __syncthreads();
  float xt[NJ];
  #pragma unroll
  for (int j=0;j<NJ;j++) xt[j] = tokbs[j];
  #pragma unroll
  for (int jp=0;jp<NJ;jp++){
    float qv = cb[(size_t)idxs[jp]*NH + t];
    #pragma unroll
    for (int j=0;j<NJ;j++) xt[j] = fmaf(tokws[jp*NJ+j], qv, xt[j]);
  }
  #pragma unroll
  for (int j=0;j<NJ;j++) Y[(size_t)(b*NJ+j)*NH + t] = xt[j];
}

// ================= fp32 channel GEMM (ENCODER only; R11-best config) =================
#define BK 8
#define ATS 68
template<int OP>
__global__ __launch_bounds__(512) void k_gemm(
  const float* __restrict__ A, const float* __restrict__ W, const float* __restrict__ bias,
  const float* __restrict__ R, float* __restrict__ OUT)
{
  __shared__ float asT[2][BK][ATS];
  __shared__ float wt[2][BK][512];
  int t = threadIdx.x;
  int m0 = blockIdx.x * 64;
  int ct = t & 63;
  int rg = t >> 6;
  int r0 = rg * 8;
  int cLo = ct*4, cHi = 256 + ct*4;
  int lane = t & 63, wv = t >> 6;
  int sar = t >> 3, sak = t & 7;
  const float* Aptr = A + (size_t)(m0+sar)*NH + sak;

  float4 accLo[8], accHi[8];
  #pragma unroll
  for (int i=0;i<8;i++){ accLo[i]=make_float4(0,0,0,0); accHi[i]=make_float4(0,0,0,0); }

  {
    g2l16(&wt[0][wv][0],   W + (size_t)wv*NH + lane*4);
    g2l16(&wt[0][wv][256], W + (size_t)wv*NH + 256 + lane*4);
    asT[0][sak][sar] = *Aptr;
  }
  __syncthreads();

  for (int kt=0; kt<64; ++kt){
    int cur = kt&1, nxt = cur^1;
    float av = 0.f;
    if (kt+1 < 64){
      int kc = (kt+1)*BK;
      av = Aptr[kc];
      g2l16(&wt[nxt][wv][0],   W + (size_t)(kc+wv)*NH + lane*4);
      g2l16(&wt[nxt][wv][256], W + (size_t)(kc+wv)*NH + 256 + lane*4);
    }
    #pragma unroll 2
    for (int k=0;k<BK;k++){
      float4 a0 = *(const float4*)&asT[cur][k][r0];
      float4 a1 = *(const float4*)&asT[cur][k][r0+4];
      float4 w0 = *(const float4*)&wt[cur][k][cLo];
      float4 w1 = *(const float4*)&wt[cur][k][cHi];
      fma4(accLo[0], a0.x, w0); fma4(accHi[0], a0.x, w1);
      fma4(accLo[1], a0.y, w0); fma4(accHi[1], a0.y, w1);
      fma4(accLo[2], a0.z, w0); fma4(accHi[2], a0.z, w1);
      fma4(accLo[3], a0.w, w0); fma4(accHi[3], a0.w, w1);
      fma4(accLo[4], a1.x, w0); fma4(accHi[4], a1.x, w1);
      fma4(accLo[5], a1.y, w0); fma4(accHi[5], a1.y, w1);
      fma4(accLo[6], a1.z, w0); fma4(accHi[6], a1.z, w1);
      fma4(accLo[7], a1.w, w0); fma4(accHi[7], a1.w, w1);
    }
    if (kt+1 < 64) asT[nxt][sak][sar] = av;
    __syncthreads();
  }
  float4 bsLo = *(const float4*)(bias + cLo);
  float4 bsHi = *(const float4*)(bias + cHi);
  #pragma unroll
  for (int i=0;i<8;i++){
    size_t row = (size_t)(m0 + r0 + i);
    float4 v0 = accLo[i], v1 = accHi[i];
    v0.x+=bsLo.x; v0.y+=bsLo.y; v0.z+=bsLo.z; v0.w+=bsLo.w;
    v1.x+=bsHi.x; v1.y+=bsHi.y; v1.z+=bsHi.z; v1.w+=bsHi.w;
    if (OP==0){
      v0.x=gelu_f(v0.x); v0.y=gelu_f(v0.y); v0.z=gelu_f(v0.z); v0.w=gelu_f(v0.w);
      v1.x=gelu_f(v1.x); v1.y=gelu_f(v1.y); v1.z=gelu_f(v1.z); v1.w=gelu_f(v1.w);
    } else if (OP==1){
      float4 r0v = *(const float4*)(R + row*NH + cLo);
      float4 r1v = *(const float4*)(R + row*NH + cHi);
      v0.x+=r0v.x; v0.y+=r0v.y; v0.z+=r0v.z; v0.w+=r0v.w;
      v1.x+=r1v.x; v1.y+=r1v.y; v1.z+=r1v.z; v1.w+=r1v.w;
    }
    *(float4*)(OUT + row*NH + cLo) = v0;
    *(float4*)(OUT + row*NH + cHi) = v1;
  }
}

// ================= W pre-split: fp32 [512x512] -> bf16 K-tiled [kt][col][32] =================
__global__ __launch_bounds__(512) void k_wsplit(const float* __restrict__ W, short* __restrict__ out){
  int kt = blockIdx.x, t = threadIdx.x;
  int kb = kt*32;
  short* dst = out + (size_t)kt*16384 + (size_t)t*32;
  #pragma unroll 8
  for (int kk=0; kk<32; ++kk)
    dst[kk] = f2bf(W[(size_t)(kb+kk)*NH + t]);
}

// ================= bf16 MFMA channel GEMM, preconverted W (DECODER) =================
#define WPCH 40
template<int OP>
__global__ __launch_bounds__(512) void k_gemm_bfp(
  const float* __restrict__ A, const short* __restrict__ Wpk, const float* __restrict__ bias,
  const float* __restrict__ R, float* __restrict__ OUT)
{
  __shared__ short Wl[512*WPCH];   // 40 KB
  __shared__ short Al[64*WPCH];    // 5 KB
  int t = threadIdx.x;
  int m0 = blockIdx.x * 64;
  int l = t & 63, w = t >> 6;
  int g = l >> 4, lm = l & 15;
  int ar = t >> 3, ak0 = (t & 7) * 4;  // A stage: row, k-base

  f32x4 acc[4][4];
  #pragma unroll
  for (int m=0;m<4;m++)
    #pragma unroll
    for (int n=0;n<4;n++){ acc[m][n][0]=0.f; acc[m][n][1]=0.f; acc[m][n][2]=0.f; acc[m][n][3]=0.f; }

  for (int kt=0; kt<16; ++kt){
    __syncthreads();               // prior frag reads done before overwrite
    const short* src = Wpk + (size_t)kt*16384;
    #pragma unroll
    for (int i=0;i<4;i++){
      int piece = t + i*512;
      s16x8 v = *(const s16x8*)(src + (size_t)piece*8);
      int col = piece >> 2, pc = piece & 3;
      *(s16x8*)&Wl[col*WPCH + pc*8] = v;
    }
    {
      float4 a4 = *(const float4*)(A + (size_t)(m0+ar)*NH + kt*32 + ak0);
      s16x4 v; v[0]=f2bf(a4.x); v[1]=f2bf(a4.y); v[2]=f2bf(a4.z); v[3]=f2bf(a4.w);
      *(s16x4*)&Al[ar*WPCH + ak0] = v;
    }
    __syncthreads();
    s16x8 af0 = *(const s16x8*)&Al[(lm +  0)*WPCH + g*8];
    s16x8 af1 = *(const s16x8*)&Al[(lm + 16)*WPCH + g*8];
    s16x8 af2 = *(const s16x8*)&Al[(lm + 32)*WPCH + g*8];
    s16x8 af3 = *(const s16x8*)&Al[(lm + 48)*WPCH + g*8];
    #pragma unroll
    for (int n=0;n<4;n++){
      int col = w*64 + n*16 + lm;
      s16x8 bfr = *(const s16x8*)&Wl[col*WPCH + g*8];
      acc[0][n] = __builtin_amdgcn_mfma_f32_16x16x32_bf16(af0, bfr, acc[0][n], 0,0,0);
      acc[1][n] = __builtin_amdgcn_mfma_f32_16x16x32_bf16(af1, bfr, acc[1][n], 0,0,0);
      acc[2][n] = __builtin_amdgcn_mfma_f32_16x16x32_bf16(af2, bfr, acc[2][n], 0,0,0);
      acc[3][n] = __builtin_amdgcn_mfma_f32_16x16x32_bf16(af3, bfr, acc[3][n], 0,0,0);
    }
  }
  #pragma unroll
  for (int n=0;n<4;n++){
    int col = w*64 + n*16 + lm;
    float bs = bias[col];
    #pragma unroll
    for (int m=0;m<4;m++){
      #pragma unroll
      for (int r=0;r<4;r++){
        int row = m0 + m*16 + g*4 + r;
        float v = acc[m][n][r] + bs;
        if (OP==0) v = gelu_f(v);
        else if (OP==1) v += R[(size_t)row*NH + col];
        OUT[(size_t)row*NH + col] = v;
      }
    }
  }
}

// ================= norms =================
__global__ void pct_norm_kernel(const float* __restrict__ e, const float* __restrict__ cb,
                                float* __restrict__ enorm, float* __restrict__ cnorm){
  int gw = (blockIdx.x*256 + threadIdx.x)>>6;
  int lane = threadIdx.x & 63;
  int nw = gridDim.x*4;
  for (int r = gw; r < 2048 + 47104; r += nw){
    const float* src = (r < 2048) ? (cb + (size_t)r*512) : (e + (size_t)(r-2048)*512);
    float4 v0 = *(const float4*)(src + lane*8);
    float4 v1 = *(const float4*)(src + lane*8 + 4);
    float q = v0.x*v0.x+v0.y*v0.y+v0.z*v0.z+v0.w*v0.w
            + v1.x*v1.x+v1.y*v1.y+v1.z*v1.z+v1.w*v1.w;
    #pragma unroll
    for (int o=32;o;o>>=1) q += __shfl_xor(q, o);
    if (lane==0){ if (r<2048) cnorm[r]=q; else enorm[r-2048]=q; }
  }
}

// ================= VQ distance GEMM + fused argmin (wave-uniform rows) =================
// Block tile 64 rows x 256 codes, K=32 chunks. 256 thr = 4 waves.
// Wave w owns rows w*16..+15 (WAVE-UNIFORM -> Et reads are LDS broadcasts);
// lane l owns cols l*4..+3 (16B stride -> conflict-free Ct reads).
// Per k: 16B per-lane LDS + broadcast feeds 64 FMAs = 4 FMA/B (old: 0.67 -> LDS-bound).
#define VBM 64
#define VBN 256
#define VBK 32
#define ETS 68
#define CTS 260
__global__ __launch_bounds__(256) void pct_vq_kernel(
  const float* __restrict__ e, const float* __restrict__ cb,
  const float* __restrict__ enorm, const float* __restrict__ cnorm,
  unsigned long long* __restrict__ packed)
{
  __shared__ float Et[VBK*ETS];   // [k][row]   8.7 KB
  __shared__ float Ct[VBK*CTS];   // [k][col]  33.3 KB
  int t = threadIdx.x;
  int row0 = blockIdx.x * VBM;
  int n00  = blockIdx.y * VBN;
  int w = t >> 6, l = t & 63;
  int r0 = w * 16;               // wave-uniform row base
  int c0 = l * 4;                // lane cols
  int er = t >> 2, eq = t & 3;   // e staging: row, k-quarter

  float4 acc[16];
  #pragma unroll
  for (int i=0;i<16;i++) acc[i] = make_float4(0,0,0,0);

  for (int kc=0; kc<512; kc+=VBK){
    __syncthreads();
    {  // stage e[64 x 32] transposed -> Et[k][row]
      const float4* src = (const float4*)(e + (size_t)(row0+er)*512 + kc + eq*8);
      float4 a = src[0], bv = src[1];
      float* d0 = Et + (eq*8)*ETS + er;
      d0[0*ETS]=a.x;  d0[1*ETS]=a.y;  d0[2*ETS]=a.z;  d0[3*ETS]=a.w;
      d0[4*ETS]=bv.x; d0[5*ETS]=bv.y; d0[6*ETS]=bv.z; d0[7*ETS]=bv.w;
    }
    {  // stage cb[256 codes x 32 k] transposed -> Ct[k][col]; thread t = code t
      const float4* src = (const float4*)(cb + (size_t)(n00+t)*512 + kc);
      #pragma unroll
      for (int q=0;q<8;q++){
        float4 v = src[q];
        float* d0 = Ct + (q*4)*CTS + t;
        d0[0*CTS]=v.x; d0[1*CTS]=v.y; d0[2*CTS]=v.z; d0[3*CTS]=v.w;
      }
    }
    __syncthreads();
    #pragma unroll 2
    for (int k=0;k<VBK;k++){
      const float* ar = &Et[k*ETS + r0];
      float4 a0 = *(const float4*)(ar);       // wave-uniform -> broadcast
      float4 a1 = *(const float4*)(ar + 4);
      float4 a2 = *(const float4*)(ar + 8);
      float4 a3 = *(const float4*)(ar + 12);
      float4 bv = *(const float4*)&Ct[k*CTS + c0];
      fma4(acc[0],  a0.x, bv); fma4(acc[1],  a0.y, bv);
      fma4(acc[2],  a0.z, bv); fma4(acc[3],  a0.w, bv);
      fma4(acc[4],  a1.x, bv); fma4(acc[5],  a1.y, bv);
      fma4(acc[6],  a1.z, bv); fma4(acc[7],  a1.w, bv);
      fma4(acc[8],  a2.x, bv); fma4(acc[9],  a2.y, bv);
      fma4(acc[10], a2.z, bv); fma4(acc[11], a2.w, bv);
      fma4(acc[12], a3.x, bv); fma4(acc[13], a3.y, bv);
      fma4(acc[14], a3.z, bv); fma4(acc[15], a3.w, bv);
    }
  }
  // per-lane candidate keys, then 64-lane reduction per row
  float4 cn4 = *(const float4*)(cnorm + n00 + c0);
  #pragma unroll
  for (int r=0;r<16;r++){
    int grow = row0 + r0 + r;
    float en = enorm[grow];                 // wave-uniform
    float4 av = acc[r];
    float d0 = (en + cn4.x) - 2.0f*av.x;
    float d1 = (en + cn4.y) - 2.0f*av.y;
    float d2 = (en + cn4.z) - 2.0f*av.z;
    float d3 = (en + cn4.w) - 2.0f*av.w;
    int cbase = n00 + c0;
    unsigned long long kk;
    kk = ((unsigned long long)__float_as_uint(d0)<<32) | (unsigned long long)(unsigned)(cbase+0);
    unsigned long long k1 = ((unsigned long long)__float_as_uint(d1)<<32) | (unsigned long long)(unsigned)(cbase+1);
    unsigned long long k2 = ((unsigned long long)__float_as_uint(d2)<<32) | (unsigned long long)(unsigned)(cbase+2);
    unsigned long long k3 = ((unsigned long long)__float_as_uint(d3)<<32) | (unsigned long long)(unsigned)(cbase+3);
    kk = k1 < kk ? k1 : kk;
    kk = k2 < kk ? k2 : kk;
    kk = k3 < kk ? k3 : kk;
    #pragma unroll
    for (int o=1;o<64;o<<=1){
      unsigned long long other = shfl_xor_u64(kk, o);
      kk = other < kk ? other : kk;
    }
    if (l==0) atomicMin(packed + grow, kk);
  }
}

// ================= idx output + latent loss =================
__global__ void pct_loss_idx_kernel(const float* __restrict__ e, const float* __restrict__ cb,
                                    const unsigned long long* __restrict__ packed,
                                    float* __restrict__ idx_out, float* __restrict__ partials){
  int t = threadIdx.x, lane = t&63;
  int gw = (blockIdx.x*256 + t)>>6;
  int nw = gridDim.x*4;
  float part = 0.f;
  for (int r=gw; r<47104; r+=nw){
    unsigned long long pk = packed[r];
    int idx = (int)(unsigned)(pk & 0xffffffffULL);
    if (lane==0) idx_out[r] = (float)idx;
    const float4* ep = (const float4*)(e + (size_t)r*512);
    const float4* cp = (const float4*)(cb + (size_t)idx*512);
    #pragma unroll
    for (int i=0;i<2;i++){
      float4 ev = ep[lane*2+i], cv = cp[lane*2+i];
      float dx=cv.x-ev.x, dy=cv.y-ev.y, dz=cv.z-ev.z, dw=cv.w-ev.w;
      part += dx*dx+dy*dy+dz*dz+dw*dw;
    }
  }
  #pragma unroll
  for (int o=32;o;o>>=1) part += __shfl_xor(part, o);
  __shared__ float wsum[4];
  if (lane==0) wsum[t>>6] = part;
  __syncthreads();
  if (t==0) partials[blockIdx.x] = wsum[0]+wsum[1]+wsum[2]+wsum[3];
}

__global__ void pct_loss_final_kernel(const float* __restrict__ partials, float* __restrict__ loss){
  float s=0.f;
  for (int i=threadIdx.x; i<256; i+=64) s += partials[i];
  #pragma unroll
  for (int o=32;o;o>>=1) s += __shfl_xor(s, o);
  if (threadIdx.x==0) *loss = s * (1.0f/(47104.0f*512.0f));
}

// ================= dec final: rec = LNf(X) @ rec_w + rec_b =================
__global__ __launch_bounds__(512) void k_decfinal(
  const float* __restrict__ X, const float* __restrict__ lnfd,
  const float* __restrict__ rec_w, const float* __restrict__ rec_b,
  float* __restrict__ rec_out)
{
  __shared__ float Lbuf[NJ*NH];          // for row_stats
  __shared__ float Ln[NJ*516];           // padded normalized rows
  __shared__ float rws[NH*9];
  __shared__ float mrs[2*NJ];
  int t = threadIdx.x, b = blockIdx.x;
  for (int i=t;i<NH*9;i+=512) rws[i] = rec_w[i];
  float xc[NJ];
  #pragma unroll
  for (int j=0;j<NJ;j++) xc[j] = X[(size_t)(b*NJ+j)*NH + t];
  row_stats512(xc, Lbuf, mrs, t);
  float gF = lnfd[t], bF = lnfd[NH+t];
  #pragma unroll
  for (int j=0;j<NJ;j++)
    Ln[j*516 + t] = fmaf((xc[j]-mrs[j])*mrs[NJ+j], gF, bF);
  __syncthreads();
  if (t < NJ*9){
    int j = t/9, c = t - j*9;
    float a = rec_b[c];
    const float* row = Ln + j*516;
    for (int h=0;h<NH;h++) a = fmaf(row[h], rws[h*9+c], a);
    rec_out[(size_t)(b*NJ+j)*9 + c] = a;
  }
}

// ================= launch =================
extern "C" void kernel_launch(void* const* d_in, const int* in_sizes, int n_in,
                              void* d_out, int out_size, void* d_ws, size_t ws_size,
                              hipStream_t stream) {
  (void)in_sizes; (void)n_in; (void)out_size; (void)ws_size;
  const float* pose        = (const float*)d_in[0];
  const float* start_w     = (const float*)d_in[1];
  const float* start_b     = (const float*)d_in[2];
  const float* enc_ln1     = (const float*)d_in[3];
  const float* enc_tw1     = (const float*)d_in[4];
  const float* enc_tb1     = (const float*)d_in[5];
  const float* enc_tw2     = (const float*)d_in[6];
  const float* enc_tb2     = (const float*)d_in[7];
  const float* enc_ln2     = (const float*)d_in[8];
  const float* enc_cw1     = (const float*)d_in[9];
  const float* enc_cb1     = (const float*)d_in[10];
  const float* enc_cw2     = (const float*)d_in[11];
  const float* enc_cb2     = (const float*)d_in[12];
  const float* enc_lnf     = (const float*)d_in[13];
  const float* tok_w       = (const float*)d_in[14];
  const float* tok_b       = (const float*)d_in[15];
  const float* feat_w      = (const float*)d_in[16];
  const float* feat_b      = (const float*)d_in[17];
  const float* codebook    = (const float*)d_in[18];
  const float* dec_tok_w   = (const float*)d_in[19];
  const float* dec_tok_b   = (const float*)d_in[20];
  const float* dec_start_w = (const float*)d_in[21];
  const float* dec_start_b = (const float*)d_in[22];
  const float* dec_ln1     = (const float*)d_in[23];
  const float* dec_tw1     = (const float*)d_in[24];
  const float* dec_tb1     = (const float*)d_in[25];
  const float* dec_tw2     = (const float*)d_in[26];
  const float* dec_tb2     = (const float*)d_in[27];
  const float* dec_ln2     = (const float*)d_in[28];
  const float* dec_cw1     = (const float*)d_in[29];
  const float* dec_cb1     = (const float*)d_in[30];
  const float* dec_cw2     = (const float*)d_in[31];
  const float* dec_cb2     = (const float*)d_in[32];
  const float* dec_lnf     = (const float*)d_in[33];
  const float* rec_w       = (const float*)d_in[34];
  const float* rec_b       = (const float*)d_in[35];

  const size_t ACT = (size_t)47104*512;     // floats per activation buffer
  float* X = (float*)d_ws;
  float* Y = X + ACT;
  unsigned long long* packed = (unsigned long long*)(Y + ACT);
  float* cnorm  = (float*)((char*)packed + (size_t)47104*8);
  float* enormp = cnorm + 2048;
  float* partials = enormp + 47104;
  short* decWpk  = (short*)(partials + 256);   // 9 x 262144 shorts = 4.7 MB

  float* rec_out  = (float*)d_out;
  float* idx_out  = rec_out + 423936;
  float* loss_out = idx_out + 47104;

  (void)hipMemsetAsync(packed, 0xFF, (size_t)47104*8, stream);

  // pre-split decoder weights to bf16 K-tiled layout (order: start, (cw1,cw2)x4)
  const size_t WSZ = (size_t)512*512;   // shorts per weight
  k_wsplit<<<16, 512, 0, stream>>>(dec_start_w, decWpk);
  for (int l=0;l<4;l++){
    k_wsplit<<<16, 512, 0, stream>>>(dec_cw1 + l*(NH*NH), decWpk + (1 + 2*l)*WSZ);
    k_wsplit<<<16, 512, 0, stream>>>(dec_cw2 + l*(NH*NH), decWpk + (2 + 2*l)*WSZ);
  }

  k_start<<<NB, 512, 0, stream>>>(pose, start_w, start_b, X);

  const int GG = 736;   // 47104 / 64
  for (int l=0;l<4;l++){
    k_tok<<<NB, 512, 0, stream>>>(X, Y,
      enc_ln1 + l*1024, enc_tw1 + l*(NJ*64), enc_tb1 + l*64,
      enc_tw2 + l*(64*NJ), enc_tb2 + l*NJ, enc_ln2 + l*1024);
    k_gemm<0><<<GG, 512, 0, stream>>>(Y, enc_cw1 + l*(NH*NH), enc_cb1 + l*NH, nullptr, Y);
    k_gemm<1><<<GG, 512, 0, stream>>>(Y, enc_cw2 + l*(NH*NH), enc_cb2 + l*NH, X, X);
  }
  k_tokf<<<NB, 512, 0, stream>>>(X, Y, enc_lnf, tok_w, tok_b);
  k_gemm<2><<<GG, 512, 0, stream>>>(Y, feat_w, feat_b, nullptr, X);   // X = e

  pct_norm_kernel<<<192, 256, 0, stream>>>(X, codebook, enormp, cnorm);
  pct_vq_kernel<<<dim3(736,8), 256, 0, stream>>>(X, codebook, enormp, cnorm, packed);
  pct_loss_idx_kernel<<<256, 256, 0, stream>>>(X, codebook, packed, idx_out, partials);
  pct_loss_final_kernel<<<1, 64, 0, stream>>>(partials, loss_out);

  k_dtok<<<NB, 512, 0, stream>>>(packed, codebook, Y, dec_tok_w, dec_tok_b);
  k_gemm_bfp<2><<<GG, 512, 0, stream>>>(Y, decWpk, dec_start_b, nullptr, X);

  for (int l=0;l<4;l++){
    k_tok<<<NB, 512, 0, stream>>>(X, Y,
      dec_ln1 + l*1024, dec_tw1 + l*(NJ*64), dec_tb1 + l*64,
      dec_tw2 + l*(64*NJ), dec_tb2 + l*NJ, dec_ln2 + l*1024);
    k_gemm_bfp<0><<<GG, 512, 0, stream>>>(Y, decWpk + (1 + 2*l)*WSZ, dec_cb1 + l*NH, nullptr, Y);
    k_gemm_bfp<1><<<GG, 512, 0, stream>>>(Y, decWpk + (2 + 2*l)*WSZ, dec_cb2 + l*NH, X, X);
  }
  k_decfinal<<<NB, 512, 0, stream>>>(X, dec_lnf, rec_w, rec_b, rec_out);
}